// Round 10
// baseline (196.416 us; speedup 1.0000x reference)
//
#include <hip/hip_runtime.h>
#include <math.h>

// ---------------------------------------------------------------------------
// 2-layer GCN. R22: shave the serial pipeline around the agg1 wall.
// R21 post-mortem: agg1 = 45.5us across SEVEN variants (random 128B-line
// gather stream, 100% line util, ~80MB beyond-L2 at the memory system's
// random-granule rate -- structural). This round, strictly-fewer-ops only:
//  - binit launch deleted: gbcursor holds RELATIVE offsets (hipMemsetAsync
//    init); scatterA adds b*CAP. h1s/t zero rows written by degcnt block 0.
//  - scatterA: 512 even blocks (CHUNK ceil(E/512)=3125) -> exactly 2
//    blocks/CU; DS-atomic critical path 52K -> 40K cyc.
//  - gemm1: 1024 thr/block (16 waves share one W1^T staging; 391 blocks
//    instead of 1563; direct-A from x as in R21).
// Unchanged: degcnt, agg1 (R20 walk: degs-load, tiers 16/24/32, raw addu,
// fused MLP), agg2 (R16 fixed-32).
// ---------------------------------------------------------------------------

#define BSHIFT 9          // 512 nodes per bucket
#define BMASK 511
#define CAP 9216          // tmp/csr slots per bucket (mean 8192, +11 sigma)
#define CAPP (CAP + 40)   // LDS csr with fast-path overread pad

typedef __bf16 bf16x8 __attribute__((ext_vector_type(8)));
typedef float f32x4 __attribute__((ext_vector_type(4)));

__device__ __forceinline__ unsigned f2b(float f) {  // fp32 -> bf16 bits (RNE)
  unsigned u = __float_as_uint(f);
  return (u + 0x7FFF + ((u >> 16) & 1)) >> 16;
}

struct f2 { float x, y; };
__device__ __forceinline__ void addu(f2& a, unsigned u) {
  a.x += __uint_as_float(u << 16);
  a.y += __uint_as_float(u);  // low 16 bits are mantissa noise (<=0.4% rel)
}
__device__ __forceinline__ void addu4(f2* a, uint4 g) {
  addu(a[0], g.x); addu(a[1], g.y); addu(a[2], g.z); addu(a[3], g.w);
}

// Block multisplit: pass1 LDS bucket hist; one global atomic per (block,bucket)
// reserves a segment (gbcursor = RELATIVE offset, memset-zeroed); pass2 places
// edges via LDS cursors. pack=(src<<9)|(dst&511).
__global__ __launch_bounds__(256) void scatterA_kernel(const int* __restrict__ src,
                                                       const int* __restrict__ dst,
                                                       int E, int chunk, int nbc,
                                                       int* __restrict__ gbcursor,
                                                       int* __restrict__ tmp) {
  __shared__ int hist[256];
  __shared__ int segcur[256];
  int tid = threadIdx.x;
  int estart = blockIdx.x * chunk;
  int eend = min(E, estart + chunk);
  hist[tid] = 0;
  __syncthreads();
  for (int i = estart + tid; i < eend; i += 256)
    atomicAdd(&hist[dst[i] >> BSHIFT], 1);
  __syncthreads();
  if (tid < nbc) {
    int c = hist[tid];
    segcur[tid] = c ? (tid * CAP + atomicAdd(&gbcursor[tid], c)) : 0;
  }
  __syncthreads();
  for (int i = estart + tid; i < eend; i += 256) {
    int d = dst[i];
    int b = d >> BSHIFT;
    int pos = atomicAdd(&segcur[b], 1);
    if (pos < (b + 1) * CAP)  // statistically impossible overflow guard
      tmp[pos] = (src[i] << BSHIFT) | (d & BMASK);
  }
}

// Per-bucket in-degree histogram -> degs (reused by agg1) + dinv (for gemm1).
// Block 0 also zeroes rows n of h1s and t (masked-gather targets).
__global__ __launch_bounds__(512) void degcnt_kernel(const int* __restrict__ tmp,
                                                     const int* __restrict__ gbcursor,
                                                     int* __restrict__ degs,
                                                     float* __restrict__ dinv,
                                                     unsigned* __restrict__ h1s,
                                                     unsigned* __restrict__ t, int n) {
  __shared__ int nh[512];
  int b = blockIdx.x, tid = threadIdx.x;
  nh[tid] = 0;
  if (b == 0) {
    if (tid < 32) h1s[(size_t)n * 32 + tid] = 0u;
    else if (tid < 40) t[(size_t)n * 8 + (tid - 32)] = 0u;
  }
  __syncthreads();
  int base = b * CAP;
  int count = min(gbcursor[b], CAP);
  for (int i = tid; i < count; i += 512) atomicAdd(&nh[tmp[base + i] & BMASK], 1);
  __syncthreads();
  int v = (b << BSHIFT) + tid;
  if (v < n) {
    degs[v] = nh[tid];
    dinv[v] = rsqrtf((float)(nh[tid] + 1));
  }
}

// h1s[row] = bf16x2-packed dinv[row] * (x[row] @ W1), via MFMA.
// 1024 thr = 16 waves share one W1^T staging; 256 rows/block. A-frags loaded
// directly from x (lane (m16,quad): x[row][ks*32+quad*8..+8], 2 float4/ks).
__global__ __launch_bounds__(1024, 2) void gemm1_kernel(const float* __restrict__ x,
                                                        const float* __restrict__ W1,
                                                        const float* __restrict__ dinv,
                                                        unsigned* __restrict__ h1s, int n) {
  __shared__ unsigned wt[64 * 68];   // wt16[n][k] bf16, stride 136 u16
  int tid = threadIdx.x;
  int vb = blockIdx.x * 256;

  unsigned short* wt16 = (unsigned short*)wt;
  const float4* wg = (const float4*)W1;
#pragma unroll
  for (int it = 0; it < 2; ++it) {
    int idx = it * 1024 + tid;         // [0,2048): k = idx>>4, n0 = (idx&15)*4
    int k = idx >> 4, n0 = (idx & 15) * 4;
    float4 wv = wg[idx];
    wt16[(n0 + 0) * 136 + k] = (unsigned short)f2b(wv.x);
    wt16[(n0 + 1) * 136 + k] = (unsigned short)f2b(wv.y);
    wt16[(n0 + 2) * 136 + k] = (unsigned short)f2b(wv.z);
    wt16[(n0 + 3) * 136 + k] = (unsigned short)f2b(wv.w);
  }
  __syncthreads();

  int lane = tid & 63, wid = tid >> 6;     // wid 0..15
  int m16 = lane & 15, quad = lane >> 4;
  int row_a = vb + wid * 16 + m16;
  int ra = (row_a < n) ? row_a : n - 1;    // clamp: garbage only affects C row
                                           // m16 (guarded at store)
  const float4* xg = (const float4*)x + (size_t)ra * 32 + quad * 2;
  unsigned a32[4][4];                      // [ks][4 u32 = 8 bf16]
#pragma unroll
  for (int ks = 0; ks < 4; ++ks) {
    float4 v0 = xg[ks * 8];
    float4 v1 = xg[ks * 8 + 1];
    a32[ks][0] = (f2b(v0.y) << 16) | f2b(v0.x);
    a32[ks][1] = (f2b(v0.w) << 16) | f2b(v0.z);
    a32[ks][2] = (f2b(v1.y) << 16) | f2b(v1.x);
    a32[ks][3] = (f2b(v1.w) << 16) | f2b(v1.z);
  }
  const unsigned* wp = wt + m16 * 68 + quad * 4;
  f32x4 acc[4] = {};
#pragma unroll
  for (int ks = 0; ks < 4; ++ks) {
    bf16x8 a = *(const bf16x8*)a32[ks];
#pragma unroll
    for (int nt = 0; nt < 4; ++nt) {
      bf16x8 b = *(const bf16x8*)(wp + nt * 16 * 68 + ks * 16);
      acc[nt] = __builtin_amdgcn_mfma_f32_16x16x32_bf16(a, b, acc[nt], 0, 0, 0);
    }
  }
  // epilogue: C[row = quad*4+reg][col = nt*16+m16]; fold dinv, pack bf16
  int rbase = vb + wid * 16 + quad * 4;
  float dvv[4];
#pragma unroll
  for (int reg = 0; reg < 4; ++reg) {
    int row = rbase + reg;
    dvv[reg] = (row < n) ? dinv[row] : 0.f;
  }
  unsigned short* h16 = (unsigned short*)h1s;
#pragma unroll
  for (int nt = 0; nt < 4; ++nt) {
    int col = nt * 16 + m16;
#pragma unroll
    for (int reg = 0; reg < 4; ++reg) {
      int row = rbase + reg;
      if (row < n)
        h16[(size_t)row * 64 + col] = (unsigned short)f2b(dvv[reg] * acc[nt][reg]);
    }
  }
}

// NQ-tier gather batch for agg1: covers slots [0, 8*NQ) of the node's edge
// list. lcsr reads up to rs+8*NQ-1 (pad-safe); masked slots pull zero row n.
template <int NQ>
__device__ __forceinline__ void gatherTier1(const uint4* __restrict__ h1s4,
                                            const int* lcsr, int rs, int e1,
                                            int e, int c, int n, f2* a0) {
  int cv0[NQ], cv1[NQ];
#pragma unroll
  for (int q = 0; q < NQ; ++q) {
    cv0[q] = lcsr[rs + q * 8 + e];
    cv1[q] = lcsr[rs + q * 8 + 4 + e];
  }
  uint4 g[2 * NQ];
#pragma unroll
  for (int q = 0; q < NQ; ++q) {
    int k0 = rs + q * 8 + e, k1 = k0 + 4;
    int s0 = (k0 < e1) ? cv0[q] : n;
    int s1 = (k1 < e1) ? cv1[q] : n;
    g[2 * q] = h1s4[(size_t)s0 * 8 + c];
    g[2 * q + 1] = h1s4[(size_t)s1 * 8 + c];
  }
#pragma unroll
  for (int k = 0; k < 2 * NQ; ++k) addu4(a0, g[k]);
}

// One 1024-thr block per 512-node bucket: load degs -> scan -> LDS-cursor
// scatter -> coalesced csr dump -> walk (half-wave per node, deg-adaptive
// tiers 16/24/32, fused b1 + lrelu + MLP(64->16)) -> t bf16. (R20-proven.)
__global__ __launch_bounds__(1024) void agg1_fused_kernel(
    const int* __restrict__ tmp, const int* __restrict__ gbcursor,
    const uint4* __restrict__ h1s4, const float* __restrict__ dinv,
    const float* __restrict__ b1, const float* __restrict__ W2,
    const int* __restrict__ degs, int* __restrict__ row_start,
    int* __restrict__ csr, unsigned* __restrict__ t, int n) {
  __shared__ int lcsr[CAPP];       // 37KB
  __shared__ int nh[512];
  __shared__ int rs_s[512];
  __shared__ int lcur[512];
  __shared__ float W2s[64 * 17];
  __shared__ float b1s[64];
  __shared__ float a_s[16][2][64];
  int b = blockIdx.x, tid = threadIdx.x;
  int base = b * CAP;
  int count = min(gbcursor[b], CAP);

  if (tid < 512) {
    int v = (b << BSHIFT) + tid;
    int d = (v < n) ? degs[v] : 0;
    nh[tid] = d;
    rs_s[tid] = d;
  }
  W2s[(tid >> 4) * 17 + (tid & 15)] = W2[tid];   // 1024 == 64*16
  if (tid < 64) b1s[tid] = b1[tid];
  __syncthreads();
  // exclusive scan of nh over 512
  for (int off = 1; off < 512; off <<= 1) {
    int a = 0;
    if (tid < 512) { a = rs_s[tid]; if (tid >= off) a += rs_s[tid - off]; }
    __syncthreads();
    if (tid < 512) rs_s[tid] = a;
    __syncthreads();
  }
  if (tid < 512) {
    int e0 = rs_s[tid] - nh[tid];   // exclusive prefix (bucket-local)
    lcur[tid] = e0;
    rs_s[tid] = e0;
    int v = (b << BSHIFT) + tid;
    if (v < n) row_start[v] = base + e0;
  }
  __syncthreads();
  // scatter into LDS csr
  for (int i = tid; i < count; i += 1024) {
    int val = tmp[base + i];
    int pos = atomicAdd(&lcur[val & BMASK], 1);
    lcsr[pos] = val >> BSHIFT;
  }
  __syncthreads();
  // coalesced dump for agg2
  for (int i = tid; i < count; i += 1024) csr[base + i] = lcsr[i];

  // walk
  int wave = tid >> 6, lane = tid & 63;
  int half = lane >> 5, sub = lane & 31;
  int e = sub >> 3, c = sub & 7;
  int j = sub & 15, grp = (sub >> 4) & 1;

#pragma unroll 1
  for (int it = 0; it < 16; ++it) {
    int nl = wave * 32 + it * 2 + half;       // 0..511
    int v = (b << BSHIFT) + nl;
    bool valid = (v < n);                     // half-uniform
    int rs = rs_s[nl];
    int deg = nh[nl];                         // 0 for v >= n
    int e1 = rs + deg;
    float dv = valid ? dinv[valid ? v : 0] : 0.f;

    f2 a0[4];
#pragma unroll
    for (int k = 0; k < 4; ++k) a0[k] = {0.f, 0.f};
    {  // self loop: e==0 lanes pull row v, others pull zero row
      int s = (valid && sub < 8) ? v : n;
      addu4(a0, h1s4[(size_t)s * 8 + c]);
    }
    // deg-adaptive fast path (wave-uniform tier on max of the two halves)
    int dm = max(deg, __shfl_xor(deg, 32, 64));
    int start;
    if (dm <= 16) {
      gatherTier1<2>(h1s4, lcsr, rs, e1, e, c, n, a0);
      start = 16;
    } else if (dm <= 24) {
      gatherTier1<3>(h1s4, lcsr, rs, e1, e, c, n, a0);
      start = 24;
    } else {
      gatherTier1<4>(h1s4, lcsr, rs, e1, e, c, n, a0);
      start = 32;
    }
    // tail: deg > 32 (rare)
    int i = rs + start;
    while (__any(i < e1)) {
      int i0 = i + e, i1 = i + 4 + e;
      int s0v = lcsr[i0];
      int s1v = lcsr[i1];
      int s0 = (i0 < e1) ? s0v : n;
      int s1 = (i1 < e1) ? s1v : n;
      addu4(a0, h1s4[(size_t)s0 * 8 + c]);
      addu4(a0, h1s4[(size_t)s1 * 8 + c]);
      i += 8;
    }
    // reduce across e (lane bits 3,4 within half)
#pragma unroll
    for (int m = 8; m <= 16; m <<= 1) {
#pragma unroll
      for (int k = 0; k < 4; ++k) {
        a0[k].x += __shfl_xor(a0[k].x, m, 64);
        a0[k].y += __shfl_xor(a0[k].y, m, 64);
      }
    }
    if (sub < 8) {  // e==0; c==sub; features 8c..8c+7
#pragma unroll
      for (int k = 0; k < 4; ++k) {
        float z0 = fmaf(dv, a0[k].x, b1s[8 * sub + 2 * k]);
        float z1 = fmaf(dv, a0[k].y, b1s[8 * sub + 2 * k + 1]);
        a_s[wave][half][8 * sub + 2 * k] = fmaxf(z0, 0.2f * z0);
        a_s[wave][half][8 * sub + 2 * k + 1] = fmaxf(z1, 0.2f * z1);
      }
    }
    // MLP 64->16: each half-lane sums 32 features (grp*16 and 32+grp*16)
    float p = 0.f;
#pragma unroll
    for (int q = 0; q < 16; ++q) {
      int f = grp * 16 + q;
      p = fmaf(a_s[wave][half][f], W2s[f * 17 + j], p);
    }
#pragma unroll
    for (int q = 0; q < 16; ++q) {
      int f = 32 + grp * 16 + q;
      p = fmaf(a_s[wave][half][f], W2s[f * 17 + j], p);
    }
    p += __shfl_xor(p, 16, 64);  // combine grp halves (lane bit 4)
    float pv = dv * p;
    float po = __shfl_xor(pv, 1, 64);
    if (valid && sub < 16 && !(sub & 1))
      t[(size_t)v * 8 + (sub >> 1)] = (f2b(po) << 16) | f2b(pv);
  }
}

// 16 lanes per node, bf16 t rows (32B). sub=lane&15: e=sub>>1 (8 edge slots),
// c=sub&1. Fast path deg<=32: 4 csr loads + 4 independent gathers. Row n of t
// is zeros. log_softmax via 8-local + xor-1 lane reduce. (R16-proven form.)
__global__ __launch_bounds__(256) void agg2_kernel(const uint4* __restrict__ t4,
                                                   const float* __restrict__ dinv,
                                                   const int* __restrict__ row_start,
                                                   const int* __restrict__ degs,
                                                   const int* __restrict__ csr,
                                                   const float* __restrict__ b2,
                                                   float* __restrict__ out, int n) {
  int idx = blockIdx.x * 256 + threadIdx.x;
  int v = idx >> 4;
  if (v >= n) return;
  int sub = threadIdx.x & 15;
  int e = sub >> 1, c = sub & 1;
  float dv = dinv[v];
  int rs = row_start[v], e1 = rs + degs[v];
  f2 A0[4];
#pragma unroll
  for (int k = 0; k < 4; ++k) A0[k] = {0.f, 0.f};
  {  // self loop
    int s = (e == 0) ? v : n;
    addu4(A0, t4[(size_t)s * 2 + c]);
  }
  int cv[4];
#pragma unroll
  for (int q = 0; q < 4; ++q) cv[q] = csr[rs + q * 8 + e];
  uint4 g[4];
#pragma unroll
  for (int q = 0; q < 4; ++q) {
    int k = rs + q * 8 + e;
    int s = (k < e1) ? cv[q] : n;
    g[q] = t4[(size_t)s * 2 + c];
  }
#pragma unroll
  for (int k = 0; k < 4; ++k) addu4(A0, g[k]);
  // tail: deg > 32 (rare; node-uniform)
  int i = rs + 32;
  while (i < e1) {
    int i0 = i + e;
    int sv = csr[i0];
    int s = (i0 < e1) ? sv : n;
    addu4(A0, t4[(size_t)s * 2 + c]);
    i += 8;
  }
#pragma unroll
  for (int m = 2; m <= 8; m <<= 1) {  // reduce across e-groups (sub bits 1..3)
#pragma unroll
    for (int k = 0; k < 4; ++k) {
      A0[k].x += __shfl_xor(A0[k].x, m, 64);
      A0[k].y += __shfl_xor(A0[k].y, m, 64);
    }
  }
  float4 bb0 = ((const float4*)b2)[c * 2];
  float4 bb1 = ((const float4*)b2)[c * 2 + 1];
  float z[8];
  z[0] = fmaf(dv, A0[0].x, bb0.x); z[1] = fmaf(dv, A0[0].y, bb0.y);
  z[2] = fmaf(dv, A0[1].x, bb0.z); z[3] = fmaf(dv, A0[1].y, bb0.w);
  z[4] = fmaf(dv, A0[2].x, bb1.x); z[5] = fmaf(dv, A0[2].y, bb1.y);
  z[6] = fmaf(dv, A0[3].x, bb1.z); z[7] = fmaf(dv, A0[3].y, bb1.w);
  float mx = z[0];
#pragma unroll
  for (int q = 1; q < 8; ++q) mx = fmaxf(mx, z[q]);
  mx = fmaxf(mx, __shfl_xor(mx, 1, 64));  // combine c halves
  float ss = 0.f;
#pragma unroll
  for (int q = 0; q < 8; ++q) ss += expf(z[q] - mx);
  ss += __shfl_xor(ss, 1, 64);
  float lg = mx + logf(ss);
  if (e == 0) {
    float4 r0 = make_float4(z[0] - lg, z[1] - lg, z[2] - lg, z[3] - lg);
    float4 r1 = make_float4(z[4] - lg, z[5] - lg, z[6] - lg, z[7] - lg);
    float4* o = (float4*)out + (size_t)v * 4 + c * 2;
    o[0] = r0;
    o[1] = r1;
  }
}

extern "C" void kernel_launch(void* const* d_in, const int* in_sizes, int n_in,
                              void* d_out, int out_size, void* d_ws, size_t ws_size,
                              hipStream_t stream) {
  const float* x = (const float*)d_in[0];
  const int* edge_index = (const int*)d_in[1];
  const float* W1 = (const float*)d_in[2];
  const float* b1 = (const float*)d_in[3];
  const float* W2 = (const float*)d_in[4];
  const float* b2 = (const float*)d_in[5];
  float* out = (float*)d_out;

  int N_ = in_sizes[0] / 128;
  int E_ = in_sizes[1] / 2;
  const int* src = edge_index;
  const int* dst = edge_index + E_;
  int NBc = (N_ + BMASK) >> BSHIFT;     // 196 buckets of 512 nodes (<= 256)
  int NSC = 512;                        // scatterA blocks (2 per CU, even)
  int CHK = (E_ + NSC - 1) / NSC;       // 3125 edges per block

  char* ws = (char*)d_ws;
  size_t off = 0;
  auto take = [&](size_t bytes) {
    void* p = ws + off;
    off += (bytes + 255) & ~(size_t)255;
    return p;
  };
  unsigned* h1s = (unsigned*)take(((size_t)N_ + 1) * 32 * 4);  // +1 zero row
  unsigned* t = (unsigned*)take(((size_t)N_ + 1) * 8 * 4);     // +1 zero row
  int* tmp = (int*)take((size_t)NBc * CAP * 4);
  int* csr = (int*)take(((size_t)NBc * CAP + 64) * 4);         // padded layout
  float* dinv = (float*)take((size_t)N_ * 4);
  int* degs = (int*)take((size_t)N_ * 4);
  int* row_start = (int*)take((size_t)N_ * 4);
  int* gbcursor = (int*)take((size_t)NBc * 4);
  (void)ws_size;

  hipMemsetAsync(gbcursor, 0, (size_t)NBc * 4, stream);  // relative cursors
  scatterA_kernel<<<NSC, 256, 0, stream>>>(src, dst, E_, CHK, NBc, gbcursor, tmp);
  degcnt_kernel<<<NBc, 512, 0, stream>>>(tmp, gbcursor, degs, dinv, h1s, t, N_);
  gemm1_kernel<<<(N_ + 255) / 256, 1024, 0, stream>>>(x, W1, dinv, h1s, N_);
  agg1_fused_kernel<<<NBc, 1024, 0, stream>>>(tmp, gbcursor, (const uint4*)h1s,
                                              dinv, b1, W2, degs, row_start, csr,
                                              t, N_);
  agg2_kernel<<<(N_ * 16 + 255) / 256, 256, 0, stream>>>((const uint4*)t, dinv,
                                                         row_start, degs, csr,
                                                         b2, out, N_);
}

// Round 12
// 191.002 us; speedup vs baseline: 1.0283x; 1.0283x over previous
//
#include <hip/hip_runtime.h>
#include <math.h>

// ---------------------------------------------------------------------------
// 2-layer GCN. R24 = R23 resubmit (R23 run died on container infra, not the
// kernel). Fuse degcnt INTO gemm1 (1:1 bucket<->block at BSHIFT=9).
// R22 post-mortem: shaves neutral (+3.4us, partly noise); R21=193.0 stands.
// agg1 = 45.5-48.5us / FETCH 79.5MB across EIGHT variants -> confirmed
// random-128B-line memory wall. Remaining lever: launch count / phase
// serialization:
//  - prep_kernel: one 1024-thr block per 512-node bucket. Issues the pass-0
//    x-row loads FIRST (HBM latency hides the hist's DS-atomic
//    serialization), then per-bucket hist -> degs/dinv, then W1^T stage +
//    MFMA for the bucket's 512 rows with dinv from LDS. Deletes one launch +
//    one tmp re-read + dinv round-trip.
//  - scatterA: R21's proven 391-block/CHUNK-4096 shape, relative cursors +
//    memset (no binit launch).
//  - agg1 (R20 walk, BSHIFT 9) and agg2 (R16 fixed-32): untouched.
// Pipeline: memset -> scatterA -> prep -> agg1 -> agg2 (4 kernels).
// ---------------------------------------------------------------------------

#define CHUNK 4096        // edges per scatterA block (391 blocks)
#define BSHIFT 9          // 512 nodes per bucket
#define BMASK 511
#define CAP 9216          // tmp/csr slots per bucket (mean 8192, +11 sigma)
#define CAPP (CAP + 40)   // LDS csr with fast-path overread pad

typedef __bf16 bf16x8 __attribute__((ext_vector_type(8)));
typedef float f32x4 __attribute__((ext_vector_type(4)));

__device__ __forceinline__ unsigned f2b(float f) {  // fp32 -> bf16 bits (RNE)
  unsigned u = __float_as_uint(f);
  return (u + 0x7FFF + ((u >> 16) & 1)) >> 16;
}

struct f2 { float x, y; };
__device__ __forceinline__ void addu(f2& a, unsigned u) {
  a.x += __uint_as_float(u << 16);
  a.y += __uint_as_float(u);  // low 16 bits are mantissa noise (<=0.4% rel)
}
__device__ __forceinline__ void addu4(f2* a, uint4 g) {
  addu(a[0], g.x); addu(a[1], g.y); addu(a[2], g.z); addu(a[3], g.w);
}

// Block multisplit: pass1 LDS bucket hist; one global atomic per (block,bucket)
// reserves a segment (gbcursor = RELATIVE offset, memset-zeroed); pass2 places
// edges via LDS cursors. pack=(src<<9)|(dst&511).
__global__ __launch_bounds__(256) void scatterA_kernel(const int* __restrict__ src,
                                                       const int* __restrict__ dst,
                                                       int E, int nbc,
                                                       int* __restrict__ gbcursor,
                                                       int* __restrict__ tmp) {
  __shared__ int hist[256];
  __shared__ int segcur[256];
  int tid = threadIdx.x;
  int estart = blockIdx.x * CHUNK;
  int eend = min(E, estart + CHUNK);
  hist[tid] = 0;
  __syncthreads();
  for (int i = estart + tid; i < eend; i += 256)
    atomicAdd(&hist[dst[i] >> BSHIFT], 1);
  __syncthreads();
  if (tid < nbc) {
    int c = hist[tid];
    segcur[tid] = c ? (tid * CAP + atomicAdd(&gbcursor[tid], c)) : 0;
  }
  __syncthreads();
  for (int i = estart + tid; i < eend; i += 256) {
    int d = dst[i];
    int b = d >> BSHIFT;
    int pos = atomicAdd(&segcur[b], 1);
    if (pos < (b + 1) * CAP)  // statistically impossible overflow guard
      tmp[pos] = (src[i] << BSHIFT) | (d & BMASK);
  }
}

// Fused degcnt + gemm1: one 1024-thr block per 512-node bucket.
// Order: issue pass-0 x loads -> hist (DS atomics hidden under HBM latency)
// -> W1^T stage -> dinv/degs -> MFMA passes 0,1 -> h1s (bf16, dinv folded).
__global__ __launch_bounds__(1024, 1) void prep_kernel(
    const int* __restrict__ tmp, const int* __restrict__ gbcursor,
    const float* __restrict__ x, const float* __restrict__ W1,
    int* __restrict__ degs, float* __restrict__ dinv,
    unsigned* __restrict__ h1s, unsigned* __restrict__ t, int n) {
  __shared__ unsigned wt[64 * 68];   // wt16[n][k] bf16, stride 136 u16
  __shared__ int nh[512];
  __shared__ float dl[512];
  int b = blockIdx.x, tid = threadIdx.x;
  if (b == 0) {  // zero rows n of h1s and t (masked-gather targets)
    if (tid < 32) h1s[(size_t)n * 32 + tid] = 0u;
    else if (tid < 40) t[(size_t)n * 8 + (tid - 32)] = 0u;
  }
  if (tid < 512) nh[tid] = 0;
  __syncthreads();

  int lane = tid & 63, wid = tid >> 6;     // wid 0..15
  int m16 = lane & 15, quad = lane >> 4;

  // pass-0 A loads issued before the hist (overlap HBM with DS atomics)
  int rloc0 = wid * 16 + m16;              // local row 0..255
  int row0 = (b << BSHIFT) + rloc0;
  int r0 = (row0 < n) ? row0 : n - 1;      // clamp; store guarded later
  const float4* xg0 = (const float4*)x + (size_t)r0 * 32 + quad * 2;
  float4 xv[8];
#pragma unroll
  for (int ks = 0; ks < 4; ++ks) {
    xv[2 * ks] = xg0[ks * 8];
    xv[2 * ks + 1] = xg0[ks * 8 + 1];
  }

  // per-bucket in-degree histogram
  int base = b * CAP;
  int count = min(gbcursor[b], CAP);
  for (int i = tid; i < count; i += 1024) atomicAdd(&nh[tmp[base + i] & BMASK], 1);

  // stage W1^T (independent of nh)
  unsigned short* wt16 = (unsigned short*)wt;
  const float4* wg = (const float4*)W1;
#pragma unroll
  for (int it = 0; it < 2; ++it) {
    int idx = it * 1024 + tid;             // [0,2048): k = idx>>4, n0=(idx&15)*4
    int k = idx >> 4, n0 = (idx & 15) * 4;
    float4 wv = wg[idx];
    wt16[(n0 + 0) * 136 + k] = (unsigned short)f2b(wv.x);
    wt16[(n0 + 1) * 136 + k] = (unsigned short)f2b(wv.y);
    wt16[(n0 + 2) * 136 + k] = (unsigned short)f2b(wv.z);
    wt16[(n0 + 3) * 136 + k] = (unsigned short)f2b(wv.w);
  }
  __syncthreads();

  if (tid < 512) {
    int v = (b << BSHIFT) + tid;
    float dvv = rsqrtf((float)(nh[tid] + 1));
    dl[tid] = dvv;
    if (v < n) { degs[v] = nh[tid]; dinv[v] = dvv; }
  }
  __syncthreads();

  const unsigned* wp = wt + m16 * 68 + quad * 4;
  unsigned short* h16 = (unsigned short*)h1s;

#pragma unroll 1
  for (int pass = 0; pass < 2; ++pass) {
    if (pass == 1) {  // load pass-1 A rows (local rows 256..511)
      int rloc1 = 256 + wid * 16 + m16;
      int row1 = (b << BSHIFT) + rloc1;
      int r1 = (row1 < n) ? row1 : n - 1;
      const float4* xg1 = (const float4*)x + (size_t)r1 * 32 + quad * 2;
#pragma unroll
      for (int ks = 0; ks < 4; ++ks) {
        xv[2 * ks] = xg1[ks * 8];
        xv[2 * ks + 1] = xg1[ks * 8 + 1];
      }
    }
    unsigned a32[4][4];                    // [ks][4 u32 = 8 bf16]
#pragma unroll
    for (int ks = 0; ks < 4; ++ks) {
      float4 v0 = xv[2 * ks], v1 = xv[2 * ks + 1];
      a32[ks][0] = (f2b(v0.y) << 16) | f2b(v0.x);
      a32[ks][1] = (f2b(v0.w) << 16) | f2b(v0.z);
      a32[ks][2] = (f2b(v1.y) << 16) | f2b(v1.x);
      a32[ks][3] = (f2b(v1.w) << 16) | f2b(v1.z);
    }
    f32x4 acc[4] = {};
#pragma unroll
    for (int ks = 0; ks < 4; ++ks) {
      bf16x8 a = *(const bf16x8*)a32[ks];
#pragma unroll
      for (int nt = 0; nt < 4; ++nt) {
        bf16x8 bb = *(const bf16x8*)(wp + nt * 16 * 68 + ks * 16);
        acc[nt] = __builtin_amdgcn_mfma_f32_16x16x32_bf16(a, bb, acc[nt], 0, 0, 0);
      }
    }
    // epilogue: C[row = quad*4+reg][col = nt*16+m16]; fold dinv (LDS), pack
    int rbloc = pass * 256 + wid * 16 + quad * 4;
    int rbase = (b << BSHIFT) + rbloc;
    float dvv[4];
#pragma unroll
    for (int reg = 0; reg < 4; ++reg) dvv[reg] = dl[rbloc + reg];
#pragma unroll
    for (int nt = 0; nt < 4; ++nt) {
      int col = nt * 16 + m16;
#pragma unroll
      for (int reg = 0; reg < 4; ++reg) {
        int row = rbase + reg;
        if (row < n)
          h16[(size_t)row * 64 + col] = (unsigned short)f2b(dvv[reg] * acc[nt][reg]);
      }
    }
  }
}

// NQ-tier gather batch for agg1: covers slots [0, 8*NQ) of the node's edge
// list. lcsr reads up to rs+8*NQ-1 (pad-safe); masked slots pull zero row n.
template <int NQ>
__device__ __forceinline__ void gatherTier1(const uint4* __restrict__ h1s4,
                                            const int* lcsr, int rs, int e1,
                                            int e, int c, int n, f2* a0) {
  int cv0[NQ], cv1[NQ];
#pragma unroll
  for (int q = 0; q < NQ; ++q) {
    cv0[q] = lcsr[rs + q * 8 + e];
    cv1[q] = lcsr[rs + q * 8 + 4 + e];
  }
  uint4 g[2 * NQ];
#pragma unroll
  for (int q = 0; q < NQ; ++q) {
    int k0 = rs + q * 8 + e, k1 = k0 + 4;
    int s0 = (k0 < e1) ? cv0[q] : n;
    int s1 = (k1 < e1) ? cv1[q] : n;
    g[2 * q] = h1s4[(size_t)s0 * 8 + c];
    g[2 * q + 1] = h1s4[(size_t)s1 * 8 + c];
  }
#pragma unroll
  for (int k = 0; k < 2 * NQ; ++k) addu4(a0, g[k]);
}

// One 1024-thr block per 512-node bucket: load degs -> scan -> LDS-cursor
// scatter -> coalesced csr dump -> walk (half-wave per node, deg-adaptive
// tiers 16/24/32, fused b1 + lrelu + MLP(64->16)) -> t bf16. (R20-proven.)
__global__ __launch_bounds__(1024) void agg1_fused_kernel(
    const int* __restrict__ tmp, const int* __restrict__ gbcursor,
    const uint4* __restrict__ h1s4, const float* __restrict__ dinv,
    const float* __restrict__ b1, const float* __restrict__ W2,
    const int* __restrict__ degs, int* __restrict__ row_start,
    int* __restrict__ csr, unsigned* __restrict__ t, int n) {
  __shared__ int lcsr[CAPP];       // 37KB
  __shared__ int nh[512];
  __shared__ int rs_s[512];
  __shared__ int lcur[512];
  __shared__ float W2s[64 * 17];
  __shared__ float b1s[64];
  __shared__ float a_s[16][2][64];
  int b = blockIdx.x, tid = threadIdx.x;
  int base = b * CAP;
  int count = min(gbcursor[b], CAP);

  if (tid < 512) {
    int v = (b << BSHIFT) + tid;
    int d = (v < n) ? degs[v] : 0;
    nh[tid] = d;
    rs_s[tid] = d;
  }
  W2s[(tid >> 4) * 17 + (tid & 15)] = W2[tid];   // 1024 == 64*16
  if (tid < 64) b1s[tid] = b1[tid];
  __syncthreads();
  // exclusive scan of nh over 512
  for (int off = 1; off < 512; off <<= 1) {
    int a = 0;
    if (tid < 512) { a = rs_s[tid]; if (tid >= off) a += rs_s[tid - off]; }
    __syncthreads();
    if (tid < 512) rs_s[tid] = a;
    __syncthreads();
  }
  if (tid < 512) {
    int e0 = rs_s[tid] - nh[tid];   // exclusive prefix (bucket-local)
    lcur[tid] = e0;
    rs_s[tid] = e0;
    int v = (b << BSHIFT) + tid;
    if (v < n) row_start[v] = base + e0;
  }
  __syncthreads();
  // scatter into LDS csr
  for (int i = tid; i < count; i += 1024) {
    int val = tmp[base + i];
    int pos = atomicAdd(&lcur[val & BMASK], 1);
    lcsr[pos] = val >> BSHIFT;
  }
  __syncthreads();
  // coalesced dump for agg2
  for (int i = tid; i < count; i += 1024) csr[base + i] = lcsr[i];

  // walk
  int wave = tid >> 6, lane = tid & 63;
  int half = lane >> 5, sub = lane & 31;
  int e = sub >> 3, c = sub & 7;
  int j = sub & 15, grp = (sub >> 4) & 1;

#pragma unroll 1
  for (int it = 0; it < 16; ++it) {
    int nl = wave * 32 + it * 2 + half;       // 0..511
    int v = (b << BSHIFT) + nl;
    bool valid = (v < n);                     // half-uniform
    int rs = rs_s[nl];
    int deg = nh[nl];                         // 0 for v >= n
    int e1 = rs + deg;
    float dv = valid ? dinv[valid ? v : 0] : 0.f;

    f2 a0[4];
#pragma unroll
    for (int k = 0; k < 4; ++k) a0[k] = {0.f, 0.f};
    {  // self loop: e==0 lanes pull row v, others pull zero row
      int s = (valid && sub < 8) ? v : n;
      addu4(a0, h1s4[(size_t)s * 8 + c]);
    }
    // deg-adaptive fast path (wave-uniform tier on max of the two halves)
    int dm = max(deg, __shfl_xor(deg, 32, 64));
    int start;
    if (dm <= 16) {
      gatherTier1<2>(h1s4, lcsr, rs, e1, e, c, n, a0);
      start = 16;
    } else if (dm <= 24) {
      gatherTier1<3>(h1s4, lcsr, rs, e1, e, c, n, a0);
      start = 24;
    } else {
      gatherTier1<4>(h1s4, lcsr, rs, e1, e, c, n, a0);
      start = 32;
    }
    // tail: deg > 32 (rare)
    int i = rs + start;
    while (__any(i < e1)) {
      int i0 = i + e, i1 = i + 4 + e;
      int s0v = lcsr[i0];
      int s1v = lcsr[i1];
      int s0 = (i0 < e1) ? s0v : n;
      int s1 = (i1 < e1) ? s1v : n;
      addu4(a0, h1s4[(size_t)s0 * 8 + c]);
      addu4(a0, h1s4[(size_t)s1 * 8 + c]);
      i += 8;
    }
    // reduce across e (lane bits 3,4 within half)
#pragma unroll
    for (int m = 8; m <= 16; m <<= 1) {
#pragma unroll
      for (int k = 0; k < 4; ++k) {
        a0[k].x += __shfl_xor(a0[k].x, m, 64);
        a0[k].y += __shfl_xor(a0[k].y, m, 64);
      }
    }
    if (sub < 8) {  // e==0; c==sub; features 8c..8c+7
#pragma unroll
      for (int k = 0; k < 4; ++k) {
        float z0 = fmaf(dv, a0[k].x, b1s[8 * sub + 2 * k]);
        float z1 = fmaf(dv, a0[k].y, b1s[8 * sub + 2 * k + 1]);
        a_s[wave][half][8 * sub + 2 * k] = fmaxf(z0, 0.2f * z0);
        a_s[wave][half][8 * sub + 2 * k + 1] = fmaxf(z1, 0.2f * z1);
      }
    }
    // MLP 64->16: each half-lane sums 32 features (grp*16 and 32+grp*16)
    float p = 0.f;
#pragma unroll
    for (int q = 0; q < 16; ++q) {
      int f = grp * 16 + q;
      p = fmaf(a_s[wave][half][f], W2s[f * 17 + j], p);
    }
#pragma unroll
    for (int q = 0; q < 16; ++q) {
      int f = 32 + grp * 16 + q;
      p = fmaf(a_s[wave][half][f], W2s[f * 17 + j], p);
    }
    p += __shfl_xor(p, 16, 64);  // combine grp halves (lane bit 4)
    float pv = dv * p;
    float po = __shfl_xor(pv, 1, 64);
    if (valid && sub < 16 && !(sub & 1))
      t[(size_t)v * 8 + (sub >> 1)] = (f2b(po) << 16) | f2b(pv);
  }
}

// 16 lanes per node, bf16 t rows (32B). sub=lane&15: e=sub>>1 (8 edge slots),
// c=sub&1. Fast path deg<=32: 4 csr loads + 4 independent gathers. Row n of t
// is zeros. log_softmax via 8-local + xor-1 lane reduce. (R16-proven form.)
__global__ __launch_bounds__(256) void agg2_kernel(const uint4* __restrict__ t4,
                                                   const float* __restrict__ dinv,
                                                   const int* __restrict__ row_start,
                                                   const int* __restrict__ degs,
                                                   const int* __restrict__ csr,
                                                   const float* __restrict__ b2,
                                                   float* __restrict__ out, int n) {
  int idx = blockIdx.x * 256 + threadIdx.x;
  int v = idx >> 4;
  if (v >= n) return;
  int sub = threadIdx.x & 15;
  int e = sub >> 1, c = sub & 1;
  float dv = dinv[v];
  int rs = row_start[v], e1 = rs + degs[v];
  f2 A0[4];
#pragma unroll
  for (int k = 0; k < 4; ++k) A0[k] = {0.f, 0.f};
  {  // self loop
    int s = (e == 0) ? v : n;
    addu4(A0, t4[(size_t)s * 2 + c]);
  }
  int cv[4];
#pragma unroll
  for (int q = 0; q < 4; ++q) cv[q] = csr[rs + q * 8 + e];
  uint4 g[4];
#pragma unroll
  for (int q = 0; q < 4; ++q) {
    int k = rs + q * 8 + e;
    int s = (k < e1) ? cv[q] : n;
    g[q] = t4[(size_t)s * 2 + c];
  }
#pragma unroll
  for (int k = 0; k < 4; ++k) addu4(A0, g[k]);
  // tail: deg > 32 (rare; node-uniform)
  int i = rs + 32;
  while (i < e1) {
    int i0 = i + e;
    int sv = csr[i0];
    int s = (i0 < e1) ? sv : n;
    addu4(A0, t4[(size_t)s * 2 + c]);
    i += 8;
  }
#pragma unroll
  for (int m = 2; m <= 8; m <<= 1) {  // reduce across e-groups (sub bits 1..3)
#pragma unroll
    for (int k = 0; k < 4; ++k) {
      A0[k].x += __shfl_xor(A0[k].x, m, 64);
      A0[k].y += __shfl_xor(A0[k].y, m, 64);
    }
  }
  float4 bb0 = ((const float4*)b2)[c * 2];
  float4 bb1 = ((const float4*)b2)[c * 2 + 1];
  float z[8];
  z[0] = fmaf(dv, A0[0].x, bb0.x); z[1] = fmaf(dv, A0[0].y, bb0.y);
  z[2] = fmaf(dv, A0[1].x, bb0.z); z[3] = fmaf(dv, A0[1].y, bb0.w);
  z[4] = fmaf(dv, A0[2].x, bb1.x); z[5] = fmaf(dv, A0[2].y, bb1.y);
  z[6] = fmaf(dv, A0[3].x, bb1.z); z[7] = fmaf(dv, A0[3].y, bb1.w);
  float mx = z[0];
#pragma unroll
  for (int q = 1; q < 8; ++q) mx = fmaxf(mx, z[q]);
  mx = fmaxf(mx, __shfl_xor(mx, 1, 64));  // combine c halves
  float ss = 0.f;
#pragma unroll
  for (int q = 0; q < 8; ++q) ss += expf(z[q] - mx);
  ss += __shfl_xor(ss, 1, 64);
  float lg = mx + logf(ss);
  if (e == 0) {
    float4 r0 = make_float4(z[0] - lg, z[1] - lg, z[2] - lg, z[3] - lg);
    float4 r1 = make_float4(z[4] - lg, z[5] - lg, z[6] - lg, z[7] - lg);
    float4* o = (float4*)out + (size_t)v * 4 + c * 2;
    o[0] = r0;
    o[1] = r1;
  }
}

extern "C" void kernel_launch(void* const* d_in, const int* in_sizes, int n_in,
                              void* d_out, int out_size, void* d_ws, size_t ws_size,
                              hipStream_t stream) {
  const float* x = (const float*)d_in[0];
  const int* edge_index = (const int*)d_in[1];
  const float* W1 = (const float*)d_in[2];
  const float* b1 = (const float*)d_in[3];
  const float* W2 = (const float*)d_in[4];
  const float* b2 = (const float*)d_in[5];
  float* out = (float*)d_out;

  int N_ = in_sizes[0] / 128;
  int E_ = in_sizes[1] / 2;
  const int* src = edge_index;
  const int* dst = edge_index + E_;
  int NBc = (N_ + BMASK) >> BSHIFT;  // 196 buckets of 512 nodes (<= 256)

  char* ws = (char*)d_ws;
  size_t off = 0;
  auto take = [&](size_t bytes) {
    void* p = ws + off;
    off += (bytes + 255) & ~(size_t)255;
    return p;
  };
  unsigned* h1s = (unsigned*)take(((size_t)N_ + 1) * 32 * 4);  // +1 zero row
  unsigned* t = (unsigned*)take(((size_t)N_ + 1) * 8 * 4);     // +1 zero row
  int* tmp = (int*)take((size_t)NBc * CAP * 4);
  int* csr = (int*)take(((size_t)NBc * CAP + 64) * 4);         // padded layout
  float* dinv = (float*)take((size_t)N_ * 4);
  int* degs = (int*)take((size_t)N_ * 4);
  int* row_start = (int*)take((size_t)N_ * 4);
  int* gbcursor = (int*)take((size_t)NBc * 4);
  (void)ws_size;

  hipMemsetAsync(gbcursor, 0, (size_t)NBc * 4, stream);  // relative cursors
  scatterA_kernel<<<(E_ + CHUNK - 1) / CHUNK, 256, 0, stream>>>(src, dst, E_, NBc,
                                                                gbcursor, tmp);
  prep_kernel<<<NBc, 1024, 0, stream>>>(tmp, gbcursor, x, W1, degs, dinv, h1s, t,
                                        N_);
  agg1_fused_kernel<<<NBc, 1024, 0, stream>>>(tmp, gbcursor, (const uint4*)h1s,
                                              dinv, b1, W2, degs, row_start, csr,
                                              t, N_);
  agg2_kernel<<<(N_ * 16 + 255) / 256, 256, 0, stream>>>((const uint4*)t, dinv,
                                                         row_start, degs, csr,
                                                         b2, out, N_);
}